// Round 1
// baseline (612.197 us; speedup 1.0000x reference)
//
#include <hip/hip_runtime.h>
#include <math.h>

#define CC 128
#define TT 3
#define HFD 256
#define WFD 256
#define PP 16
#define NPAIR 2048
#define PATCH_ELEMS (CC * PP * PP)        // 32768
#define CH_STRIDE (TT * HFD * WFD)        // 196608
#define BLOCK 256

// ---------------- Kernel A: per-patch min/max ----------------
// grid = 2*NPAIR blocks; block b < NPAIR -> patch from (ts1,ys1,xs1)[b],
// else patch from (ts2,ys2,xs2)[b-NPAIR]. Output mm[2*b], mm[2*b+1].
__global__ __launch_bounds__(BLOCK) void patch_minmax_kernel(
    const float* __restrict__ resp,
    const int* __restrict__ ts1, const int* __restrict__ ys1, const int* __restrict__ xs1,
    const int* __restrict__ ts2, const int* __restrict__ ys2, const int* __restrict__ xs2,
    float* __restrict__ mm) {
    int p = blockIdx.x;
    int i = (p < NPAIR) ? p : (p - NPAIR);
    int t, y, x;
    if (p < NPAIR) { t = ts1[i]; y = ys1[i]; x = xs1[i]; }
    else           { t = ts2[i]; y = ys2[i]; x = xs2[i]; }

    const float* base = resp + ((size_t)t * HFD + (size_t)y) * WFD + (size_t)x;

    float mn = INFINITY, mx = -INFINITY;
    #pragma unroll 4
    for (int e = threadIdx.x; e < PATCH_ELEMS; e += BLOCK) {
        int c  = e >> 8;          // 256 elems per channel (16x16)
        int r  = e & 255;
        int dy = r >> 4;
        int dx = r & 15;
        float v = base[c * CH_STRIDE + dy * WFD + dx];
        mn = fminf(mn, v);
        mx = fmaxf(mx, v);
    }
    // wave (64-lane) reduce
    for (int off = 32; off > 0; off >>= 1) {
        mn = fminf(mn, __shfl_down(mn, off));
        mx = fmaxf(mx, __shfl_down(mx, off));
    }
    __shared__ float smn[BLOCK / 64], smx[BLOCK / 64];
    int wave = threadIdx.x >> 6;
    if ((threadIdx.x & 63) == 0) { smn[wave] = mn; smx[wave] = mx; }
    __syncthreads();
    if (threadIdx.x == 0) {
        mn = fminf(fminf(smn[0], smn[1]), fminf(smn[2], smn[3]));
        mx = fmaxf(fmaxf(smx[0], smx[1]), fmaxf(smx[2], smx[3]));
        mm[2 * p]     = mn;
        mm[2 * p + 1] = mx;
    }
}

// ---------------- Kernel B: per-pair loss ----------------
// grid = NPAIR blocks. Reads both patches, normalizes with precomputed
// min/max, accumulates |n1-n2|^pw, writes the per-pair loss term.
__global__ __launch_bounds__(BLOCK) void pair_loss_kernel(
    const float* __restrict__ resp,
    const int* __restrict__ ts1, const int* __restrict__ ys1, const int* __restrict__ xs1,
    const int* __restrict__ ts2, const int* __restrict__ ys2, const int* __restrict__ xs2,
    const int* __restrict__ pair_type,
    const float* __restrict__ powers,
    const float* __restrict__ plus,
    const float* __restrict__ mm,
    float* __restrict__ per_out) {
    int i = blockIdx.x;
    int t1 = ts1[i], y1 = ys1[i], x1 = xs1[i];
    int t2 = ts2[i], y2 = ys2[i], x2 = xs2[i];

    float mn1 = mm[2 * i],             mx1 = mm[2 * i + 1];
    float mn2 = mm[2 * (i + NPAIR)],   mx2 = mm[2 * (i + NPAIR) + 1];
    float rg1 = mx1 - mn1, rg2 = mx2 - mn2;
    // normalize: n = rng!=0 ? (v-mn)/rng : v   (branchless as (v-sh)*sc)
    float sc1 = (rg1 != 0.0f) ? (1.0f / rg1) : 1.0f;
    float sh1 = (rg1 != 0.0f) ? mn1 : 0.0f;
    float sc2 = (rg2 != 0.0f) ? (1.0f / rg2) : 1.0f;
    float sh2 = (rg2 != 0.0f) ? mn2 : 0.0f;

    int   ptype = pair_type[i];
    float pw    = powers[ptype];

    const float* b1 = resp + ((size_t)t1 * HFD + (size_t)y1) * WFD + (size_t)x1;
    const float* b2 = resp + ((size_t)t2 * HFD + (size_t)y2) * WFD + (size_t)x2;

    float acc = 0.0f;
    #pragma unroll 4
    for (int e = threadIdx.x; e < PATCH_ELEMS; e += BLOCK) {
        int c  = e >> 8;
        int r  = e & 255;
        int off = c * CH_STRIDE + (r >> 4) * WFD + (r & 15);
        float v1 = b1[off];
        float v2 = b2[off];
        float n1 = (v1 - sh1) * sc1;
        float n2 = (v2 - sh2) * sc2;
        float ad = fabsf(n1 - n2);
        acc += __powf(ad, pw);   // ad in [0,1], pw in [1,2): exp2(pw*log2(ad)); 0 -> 0
    }
    // block sum-reduce
    for (int off = 32; off > 0; off >>= 1) acc += __shfl_down(acc, off);
    __shared__ float ssum[BLOCK / 64];
    int wave = threadIdx.x >> 6;
    if ((threadIdx.x & 63) == 0) ssum[wave] = acc;
    __syncthreads();
    if (threadIdx.x == 0) {
        float total = ssum[0] + ssum[1] + ssum[2] + ssum[3];
        float d = total * (1.0f / (float)PATCH_ELEMS);
        float per = (ptype == 2) ? d : (1.0f / (1.0f + d));
        per += (ptype == 0) ? 0.0f : plus[0] * 0.5f;
        per_out[i] = per;
    }
}

// ---------------- Kernel C: mean over pairs ----------------
__global__ __launch_bounds__(BLOCK) void final_mean_kernel(
    const float* __restrict__ per_out, float* __restrict__ out) {
    float acc = 0.0f;
    for (int i = threadIdx.x; i < NPAIR; i += BLOCK) acc += per_out[i];
    for (int off = 32; off > 0; off >>= 1) acc += __shfl_down(acc, off);
    __shared__ float ssum[BLOCK / 64];
    int wave = threadIdx.x >> 6;
    if ((threadIdx.x & 63) == 0) ssum[wave] = acc;
    __syncthreads();
    if (threadIdx.x == 0) {
        float total = ssum[0] + ssum[1] + ssum[2] + ssum[3];
        out[0] = total * (1.0f / (float)NPAIR);
    }
}

extern "C" void kernel_launch(void* const* d_in, const int* in_sizes, int n_in,
                              void* d_out, int out_size, void* d_ws, size_t ws_size,
                              hipStream_t stream) {
    const float* resp      = (const float*)d_in[0];
    const int*   ys1       = (const int*)d_in[1];
    const int*   xs1       = (const int*)d_in[2];
    const int*   ts1       = (const int*)d_in[3];
    const int*   ys2       = (const int*)d_in[4];
    const int*   xs2       = (const int*)d_in[5];
    const int*   ts2       = (const int*)d_in[6];
    const int*   pair_type = (const int*)d_in[7];
    const float* powers    = (const float*)d_in[8];
    const float* plus      = (const float*)d_in[9];
    float*       out       = (float*)d_out;

    float* mm      = (float*)d_ws;                 // 2*2*NPAIR floats = 32 KB
    float* per_out = mm + 4 * NPAIR;               // NPAIR floats = 8 KB

    patch_minmax_kernel<<<2 * NPAIR, BLOCK, 0, stream>>>(
        resp, ts1, ys1, xs1, ts2, ys2, xs2, mm);

    pair_loss_kernel<<<NPAIR, BLOCK, 0, stream>>>(
        resp, ts1, ys1, xs1, ts2, ys2, xs2, pair_type, powers, plus, mm, per_out);

    final_mean_kernel<<<1, BLOCK, 0, stream>>>(per_out, out);
}

// Round 3
// 380.519 us; speedup vs baseline: 1.6088x; 1.6088x over previous
//
#include <hip/hip_runtime.h>
#include <math.h>

#define CC 128
#define TT 3
#define HFD 256
#define WFD 256
#define PP 16
#define NPAIR 2048
#define HW (HFD * WFD)            // 65536 positions per t-slice
#define POS (TT * HW)             // 196608 positions total
#define CH_STRIDE POS             // channel stride in floats ([C,T,H,W])
#define PATCH_ELEMS (CC * PP * PP)
#define BLOCK 256

// ---------- M1: per-position min/max over channels (coalesced, reads 100 MB once) ----
__global__ __launch_bounds__(BLOCK) void chan_minmax_kernel(
    const float* __restrict__ resp,
    float* __restrict__ cmn, float* __restrict__ cmx) {
    int p = blockIdx.x * BLOCK + threadIdx.x;          // [0, POS)
    float mn = INFINITY, mx = -INFINITY;
    #pragma unroll 8
    for (int c = 0; c < CC; ++c) {
        float v = resp[(size_t)c * CH_STRIDE + p];
        mn = fminf(mn, v);
        mx = fmaxf(mx, v);
    }
    cmn[p] = mn;
    cmx[p] = mx;
}

// ---------- M2: horizontal sliding window min/max over 16 (1.5 MB, L2-hot) ----------
__global__ __launch_bounds__(BLOCK) void hwin_minmax_kernel(
    const float* __restrict__ cmn, const float* __restrict__ cmx,
    float* __restrict__ hmn, float* __restrict__ hmx) {
    int p = blockIdx.x * BLOCK + threadIdx.x;          // t*HW + y*W + x
    int x = p & (WFD - 1);
    int rowbase = p - x;
    float mn = INFINITY, mx = -INFINITY;
    #pragma unroll
    for (int j = 0; j < PP; ++j) {
        int xx = x + j;
        xx = (xx < WFD) ? xx : (WFD - 1);              // clamp; clamped range never used
        mn = fminf(mn, cmn[rowbase + xx]);
        mx = fmaxf(mx, cmx[rowbase + xx]);
    }
    hmn[p] = mn;
    hmx[p] = mx;
}

// ---------- M3: vertical sliding window min/max over 16 -> per-patch min/max --------
__global__ __launch_bounds__(BLOCK) void vwin_minmax_kernel(
    const float* __restrict__ hmn, const float* __restrict__ hmx,
    float* __restrict__ pmn, float* __restrict__ pmx) {
    int p = blockIdx.x * BLOCK + threadIdx.x;          // t*HW + y*W + x
    int t   = p >> 16;
    int rem = p & (HW - 1);
    int y   = rem >> 8;
    int x   = rem & (WFD - 1);
    int base = t * HW + x;
    float mn = INFINITY, mx = -INFINITY;
    #pragma unroll
    for (int j = 0; j < PP; ++j) {
        int yy = y + j;
        yy = (yy < HFD) ? yy : (HFD - 1);              // clamp; clamped range never used
        mn = fminf(mn, hmn[base + yy * WFD]);
        mx = fmaxf(mx, hmx[base + yy * WFD]);
    }
    pmn[p] = mn;
    pmx[p] = mx;
}

// ---------- L: per-pair loss (row-based loads, native exp2/log2 pow) ----------------
__global__ __launch_bounds__(BLOCK) void pair_loss_kernel(
    const float* __restrict__ resp,
    const int* __restrict__ ts1, const int* __restrict__ ys1, const int* __restrict__ xs1,
    const int* __restrict__ ts2, const int* __restrict__ ys2, const int* __restrict__ xs2,
    const int* __restrict__ pair_type,
    const float* __restrict__ powers,
    const float* __restrict__ plus,
    const float* __restrict__ pmn, const float* __restrict__ pmx,
    float* __restrict__ per_out) {
    int i = blockIdx.x;
    int t1 = ts1[i], y1 = ys1[i], x1 = xs1[i];
    int t2 = ts2[i], y2 = ys2[i], x2 = xs2[i];

    int p1idx = t1 * HW + y1 * WFD + x1;
    int p2idx = t2 * HW + y2 * WFD + x2;
    float mn1 = pmn[p1idx], mx1 = pmx[p1idx];
    float mn2 = pmn[p2idx], mx2 = pmx[p2idx];
    float rg1 = mx1 - mn1, rg2 = mx2 - mn2;
    float sc1 = (rg1 != 0.0f) ? (1.0f / rg1) : 1.0f;
    float sh1 = (rg1 != 0.0f) ? mn1 : 0.0f;
    float sc2 = (rg2 != 0.0f) ? (1.0f / rg2) : 1.0f;
    float sh2 = (rg2 != 0.0f) ? mn2 : 0.0f;
    // diff = (v1-sh1)*sc1 - (v2-sh2)*sc2 = v1*sc1 + v2*(-sc2) + K
    float nsc2 = -sc2;
    float K = sh2 * sc2 - sh1 * sc1;

    int   ptype = pair_type[i];
    float pw    = powers[ptype];

    const float* b1 = resp + (size_t)t1 * HW + (size_t)y1 * WFD + (size_t)x1;
    const float* b2 = resp + (size_t)t2 * HW + (size_t)y2 * WFD + (size_t)x2;

    float acc = 0.0f;
    // 2048 rows per patch (128 c x 16 dy); each thread: 8 rows, 16 floats each.
    for (int r = threadIdx.x; r < CC * PP; r += BLOCK) {
        int c  = r >> 4;
        int dy = r & 15;
        const float* q1 = b1 + (size_t)c * CH_STRIDE + dy * WFD;
        const float* q2 = b2 + (size_t)c * CH_STRIDE + dy * WFD;
        #pragma unroll
        for (int dx = 0; dx < PP; ++dx) {
            float d = fmaf(q1[dx], sc1, fmaf(q2[dx], nsc2, K));
            // |d|^pw = exp2(pw * log2(|d|)); d==0 -> exp2(-inf) = 0, correct.
            acc += __builtin_amdgcn_exp2f(pw * __builtin_amdgcn_logf(fabsf(d)));
        }
    }
    // block sum-reduce
    for (int off = 32; off > 0; off >>= 1) acc += __shfl_down(acc, off);
    __shared__ float ssum[BLOCK / 64];
    int wave = threadIdx.x >> 6;
    if ((threadIdx.x & 63) == 0) ssum[wave] = acc;
    __syncthreads();
    if (threadIdx.x == 0) {
        float total = ssum[0] + ssum[1] + ssum[2] + ssum[3];
        float dmean = total * (1.0f / (float)PATCH_ELEMS);
        float per = (ptype == 2) ? dmean : (1.0f / (1.0f + dmean));
        per += (ptype == 0) ? 0.0f : plus[0] * 0.5f;
        per_out[i] = per;
    }
}

// ---------- Final mean over pairs ---------------------------------------------------
__global__ __launch_bounds__(BLOCK) void final_mean_kernel(
    const float* __restrict__ per_out, float* __restrict__ out) {
    float acc = 0.0f;
    for (int i = threadIdx.x; i < NPAIR; i += BLOCK) acc += per_out[i];
    for (int off = 32; off > 0; off >>= 1) acc += __shfl_down(acc, off);
    __shared__ float ssum[BLOCK / 64];
    int wave = threadIdx.x >> 6;
    if ((threadIdx.x & 63) == 0) ssum[wave] = acc;
    __syncthreads();
    if (threadIdx.x == 0) {
        float total = ssum[0] + ssum[1] + ssum[2] + ssum[3];
        out[0] = total * (1.0f / (float)NPAIR);
    }
}

extern "C" void kernel_launch(void* const* d_in, const int* in_sizes, int n_in,
                              void* d_out, int out_size, void* d_ws, size_t ws_size,
                              hipStream_t stream) {
    const float* resp      = (const float*)d_in[0];
    const int*   ys1       = (const int*)d_in[1];
    const int*   xs1       = (const int*)d_in[2];
    const int*   ts1       = (const int*)d_in[3];
    const int*   ys2       = (const int*)d_in[4];
    const int*   xs2       = (const int*)d_in[5];
    const int*   ts2       = (const int*)d_in[6];
    const int*   pair_type = (const int*)d_in[7];
    const float* powers    = (const float*)d_in[8];
    const float* plus      = (const float*)d_in[9];
    float*       out       = (float*)d_out;

    // Workspace layout (floats): 4 x POS buffers + per-pair output = ~3.1 MB
    float* buf0    = (float*)d_ws;           // cmn, later pmn
    float* buf1    = buf0 + POS;             // cmx, later pmx
    float* buf2    = buf1 + POS;             // hmn
    float* buf3    = buf2 + POS;             // hmx
    float* per_out = buf3 + POS;             // NPAIR floats

    int posBlocks = POS / BLOCK;             // 768

    chan_minmax_kernel<<<posBlocks, BLOCK, 0, stream>>>(resp, buf0, buf1);
    hwin_minmax_kernel<<<posBlocks, BLOCK, 0, stream>>>(buf0, buf1, buf2, buf3);
    // M3 reads buf2/buf3, writes patch min/max into buf0/buf1 (no longer needed)
    vwin_minmax_kernel<<<posBlocks, BLOCK, 0, stream>>>(buf2, buf3, buf0, buf1);

    pair_loss_kernel<<<NPAIR, BLOCK, 0, stream>>>(
        resp, ts1, ys1, xs1, ts2, ys2, xs2, pair_type, powers, plus,
        buf0, buf1, per_out);

    final_mean_kernel<<<1, BLOCK, 0, stream>>>(per_out, out);
}

// Round 4
// 218.540 us; speedup vs baseline: 2.8013x; 1.7412x over previous
//
#include <hip/hip_runtime.h>
#include <math.h>

#define CC 128
#define TT 3
#define HFD 256
#define WFD 256
#define PP 16
#define NPAIR 2048
#define HW (HFD * WFD)            // 65536 positions per t-slice
#define POS (TT * HW)             // 196608 positions total
#define CH_STRIDE POS             // channel stride in floats ([C,T,H,W])
#define PATCH_ELEMS (CC * PP * PP)
#define BLOCK 256
#define TPOS 64                   // positions per transpose tile

typedef _Float16 half8 __attribute__((ext_vector_type(8)));

// ---------- K1: fused transpose [C,THW]->[THW,C] fp16 + per-position channel min/max
__global__ __launch_bounds__(BLOCK) void transpose_minmax_kernel(
    const float* __restrict__ resp,
    _Float16* __restrict__ rt,
    float* __restrict__ cmn, float* __restrict__ cmx) {
    __shared__ _Float16 tile[TPOS][130];        // +2 pad: conflict-free r/w
    __shared__ float smn[4][TPOS], smx[4][TPOS];

    int p0   = blockIdx.x * TPOS;
    int lane = threadIdx.x & 63;                // position within tile
    int c0   = threadIdx.x >> 6;                // 0..3 channel phase
    int p    = p0 + lane;

    float mn = INFINITY, mx = -INFINITY;
    #pragma unroll 8
    for (int c = c0; c < CC; c += 4) {
        float v = resp[(size_t)c * CH_STRIDE + p];
        mn = fminf(mn, v);
        mx = fmaxf(mx, v);
        tile[lane][c] = (_Float16)v;
    }
    smn[c0][lane] = mn;
    smx[c0][lane] = mx;
    __syncthreads();
    if (threadIdx.x < TPOS) {
        int l = threadIdx.x;
        cmn[p0 + l] = fminf(fminf(smn[0][l], smn[1][l]), fminf(smn[2][l], smn[3][l]));
        cmx[p0 + l] = fmaxf(fmaxf(smx[0][l], smx[1][l]), fmaxf(smx[2][l], smx[3][l]));
    }
    // write tile out as [pos][c] fp16, coalesced 4B stores
    unsigned int* out32 = (unsigned int*)rt;
    #pragma unroll
    for (int j = 0; j < 16; ++j) {
        int u2  = j * BLOCK + threadIdx.x;      // half2 index within tile [0,4096)
        int pos = u2 >> 6;                      // 64 half2 per position
        int c2  = u2 & 63;
        unsigned int w = *(const unsigned int*)&tile[pos][2 * c2];
        out32[(((size_t)(p0 + pos)) << 6) + c2] = w;
    }
}

// ---------- K2: horizontal sliding window min/max over 16 ----------
__global__ __launch_bounds__(BLOCK) void hwin_minmax_kernel(
    const float* __restrict__ cmn, const float* __restrict__ cmx,
    float* __restrict__ hmn, float* __restrict__ hmx) {
    int p = blockIdx.x * BLOCK + threadIdx.x;
    int x = p & (WFD - 1);
    int rowbase = p - x;
    float mn = INFINITY, mx = -INFINITY;
    #pragma unroll
    for (int j = 0; j < PP; ++j) {
        int xx = x + j;
        xx = (xx < WFD) ? xx : (WFD - 1);       // clamp; clamped range never used
        mn = fminf(mn, cmn[rowbase + xx]);
        mx = fmaxf(mx, cmx[rowbase + xx]);
    }
    hmn[p] = mn;
    hmx[p] = mx;
}

// ---------- K3: vertical sliding window min/max over 16 -> per-patch min/max ----------
__global__ __launch_bounds__(BLOCK) void vwin_minmax_kernel(
    const float* __restrict__ hmn, const float* __restrict__ hmx,
    float* __restrict__ pmn, float* __restrict__ pmx) {
    int p = blockIdx.x * BLOCK + threadIdx.x;
    int t   = p >> 16;
    int rem = p & (HW - 1);
    int y   = rem >> 8;
    int x   = rem & (WFD - 1);
    int base = t * HW + x;
    float mn = INFINITY, mx = -INFINITY;
    #pragma unroll
    for (int j = 0; j < PP; ++j) {
        int yy = y + j;
        yy = (yy < HFD) ? yy : (HFD - 1);       // clamp; clamped range never used
        mn = fminf(mn, hmn[base + yy * WFD]);
        mx = fmaxf(mx, hmx[base + yy * WFD]);
    }
    pmn[p] = mn;
    pmx[p] = mx;
}

// ---------- K4: per-pair loss on fp16 channel-last tensor ----------
__global__ __launch_bounds__(BLOCK) void pair_loss_kernel(
    const _Float16* __restrict__ rt,
    const int* __restrict__ ts1, const int* __restrict__ ys1, const int* __restrict__ xs1,
    const int* __restrict__ ts2, const int* __restrict__ ys2, const int* __restrict__ xs2,
    const int* __restrict__ pair_type,
    const float* __restrict__ powers,
    const float* __restrict__ plus,
    const float* __restrict__ pmn, const float* __restrict__ pmx,
    float* __restrict__ per_out) {
    int i = blockIdx.x;
    int t1 = ts1[i], y1 = ys1[i], x1 = xs1[i];
    int t2 = ts2[i], y2 = ys2[i], x2 = xs2[i];

    int p1 = t1 * HW + y1 * WFD + x1;
    int p2 = t2 * HW + y2 * WFD + x2;
    float mn1 = pmn[p1], mx1 = pmx[p1];
    float mn2 = pmn[p2], mx2 = pmx[p2];
    float rg1 = mx1 - mn1, rg2 = mx2 - mn2;
    float sc1 = (rg1 != 0.0f) ? (1.0f / rg1) : 1.0f;
    float sh1 = (rg1 != 0.0f) ? mn1 : 0.0f;
    float sc2 = (rg2 != 0.0f) ? (1.0f / rg2) : 1.0f;
    float sh2 = (rg2 != 0.0f) ? mn2 : 0.0f;
    float nsc2 = -sc2;
    float K = sh2 * sc2 - sh1 * sc1;

    int   ptype = pair_type[i];
    float pw    = powers[ptype];

    // thread t: dx = t>>4 (0..15), channels [8*(t&15), +8), loop dy=0..15
    int dx = threadIdx.x >> 4;
    int c8 = (threadIdx.x & 15) * 8;
    const half8* A = (const half8*)(rt + (((size_t)(p1 + dx)) << 7) + c8);
    const half8* B = (const half8*)(rt + (((size_t)(p2 + dx)) << 7) + c8);
    const int STR = WFD * CC / 8;               // half8 stride per dy step = 4096

    float acc = 0.0f;
    #pragma unroll
    for (int j = 0; j < PP; ++j) {
        half8 u = A[(size_t)j * STR];
        half8 v = B[(size_t)j * STR];
        #pragma unroll
        for (int k = 0; k < 8; ++k) {
            float d = fmaf((float)u[k], sc1, fmaf((float)v[k], nsc2, K));
            // |d|^pw = exp2(pw * log2(|d|)); d==0 -> exp2(-inf) = 0, correct.
            acc += __builtin_amdgcn_exp2f(pw * __builtin_amdgcn_logf(fabsf(d)));
        }
    }
    // block sum-reduce
    for (int off = 32; off > 0; off >>= 1) acc += __shfl_down(acc, off);
    __shared__ float ssum[BLOCK / 64];
    int wave = threadIdx.x >> 6;
    if ((threadIdx.x & 63) == 0) ssum[wave] = acc;
    __syncthreads();
    if (threadIdx.x == 0) {
        float total = ssum[0] + ssum[1] + ssum[2] + ssum[3];
        float dmean = total * (1.0f / (float)PATCH_ELEMS);
        float per = (ptype == 2) ? dmean : (1.0f / (1.0f + dmean));
        per += (ptype == 0) ? 0.0f : plus[0] * 0.5f;
        per_out[i] = per;
    }
}

// ---------- K5: mean over pairs ----------
__global__ __launch_bounds__(BLOCK) void final_mean_kernel(
    const float* __restrict__ per_out, float* __restrict__ out) {
    float acc = 0.0f;
    for (int i = threadIdx.x; i < NPAIR; i += BLOCK) acc += per_out[i];
    for (int off = 32; off > 0; off >>= 1) acc += __shfl_down(acc, off);
    __shared__ float ssum[BLOCK / 64];
    int wave = threadIdx.x >> 6;
    if ((threadIdx.x & 63) == 0) ssum[wave] = acc;
    __syncthreads();
    if (threadIdx.x == 0) {
        float total = ssum[0] + ssum[1] + ssum[2] + ssum[3];
        out[0] = total * (1.0f / (float)NPAIR);
    }
}

extern "C" void kernel_launch(void* const* d_in, const int* in_sizes, int n_in,
                              void* d_out, int out_size, void* d_ws, size_t ws_size,
                              hipStream_t stream) {
    const float* resp      = (const float*)d_in[0];
    const int*   ys1       = (const int*)d_in[1];
    const int*   xs1       = (const int*)d_in[2];
    const int*   ts1       = (const int*)d_in[3];
    const int*   ys2       = (const int*)d_in[4];
    const int*   xs2       = (const int*)d_in[5];
    const int*   ts2       = (const int*)d_in[6];
    const int*   pair_type = (const int*)d_in[7];
    const float* powers    = (const float*)d_in[8];
    const float* plus      = (const float*)d_in[9];
    float*       out       = (float*)d_out;

    // Workspace: fp16 tensor (50.3 MB) + 4 x POS float buffers (3.1 MB) + per_out
    _Float16* rt   = (_Float16*)d_ws;
    float* buf0    = (float*)(rt + (size_t)POS * CC);  // cmn, later pmn
    float* buf1    = buf0 + POS;                       // cmx, later pmx
    float* buf2    = buf1 + POS;                       // hmn
    float* buf3    = buf2 + POS;                       // hmx
    float* per_out = buf3 + POS;                       // NPAIR floats

    int posBlocks = POS / BLOCK;                       // 768

    transpose_minmax_kernel<<<POS / TPOS, BLOCK, 0, stream>>>(resp, rt, buf0, buf1);
    hwin_minmax_kernel<<<posBlocks, BLOCK, 0, stream>>>(buf0, buf1, buf2, buf3);
    vwin_minmax_kernel<<<posBlocks, BLOCK, 0, stream>>>(buf2, buf3, buf0, buf1);

    pair_loss_kernel<<<NPAIR, BLOCK, 0, stream>>>(
        rt, ts1, ys1, xs1, ts2, ys2, xs2, pair_type, powers, plus,
        buf0, buf1, per_out);

    final_mean_kernel<<<1, BLOCK, 0, stream>>>(per_out, out);
}

// Round 5
// 192.572 us; speedup vs baseline: 3.1791x; 1.1348x over previous
//
#include <hip/hip_runtime.h>
#include <math.h>

#define CC 128
#define TT 3
#define HFD 256
#define WFD 256
#define PP 16
#define NPAIR 2048
#define HW (HFD * WFD)            // 65536 positions per t-slice
#define POS (TT * HW)             // 196608 positions total
#define CH_STRIDE POS             // channel stride in floats ([C,T,H,W])
#define PATCH_ELEMS (CC * PP * PP)
#define BLOCK 256
#define TP 256                    // positions per transpose tile

typedef float floatx2 __attribute__((ext_vector_type(2)));
typedef float floatx4 __attribute__((ext_vector_type(4)));

// ---------- K1: fused transpose [C,THW]fp32 -> [THW,C]fp8 + per-position chan min/max
// Each lane reads float4 (4 positions) per channel -> 1 KB contiguous per wave-load.
// Channel quads packed into one dword of fp8 e4m3.
__global__ __launch_bounds__(BLOCK) void transpose_minmax_kernel(
    const float* __restrict__ resp,
    unsigned int* __restrict__ rt32,          // fp8 tensor, 32 dwords per position
    float* __restrict__ cmn, float* __restrict__ cmx) {
    __shared__ unsigned int tile32[TP][33];   // [pos][chan-quad], +1 pad
    __shared__ float smn[4][TP], smx[4][TP];

    int p0 = blockIdx.x * TP;
    int pc = threadIdx.x & 63;                // float4 position chunk
    int ph = threadIdx.x >> 6;                // channel phase 0..3

    const float* bp = resp + p0 + 4 * pc;

    float mn0 = INFINITY, mn1 = INFINITY, mn2 = INFINITY, mn3 = INFINITY;
    float mx0 = -INFINITY, mx1 = -INFINITY, mx2 = -INFINITY, mx3 = -INFINITY;

    #pragma unroll
    for (int k = 0; k < 8; ++k) {
        int q = k * 4 + ph;                   // channel quad index [0,32)
        floatx4 l0 = *(const floatx4*)(bp + (size_t)(4 * q + 0) * CH_STRIDE);
        floatx4 l1 = *(const floatx4*)(bp + (size_t)(4 * q + 1) * CH_STRIDE);
        floatx4 l2 = *(const floatx4*)(bp + (size_t)(4 * q + 2) * CH_STRIDE);
        floatx4 l3 = *(const floatx4*)(bp + (size_t)(4 * q + 3) * CH_STRIDE);
        #pragma unroll
        for (int j = 0; j < 4; ++j) {
            float v0 = l0[j], v1 = l1[j], v2 = l2[j], v3 = l3[j];
            float mnj = fminf(fminf(v0, v1), fminf(v2, v3));
            float mxj = fmaxf(fmaxf(v0, v1), fmaxf(v2, v3));
            if (j == 0) { mn0 = fminf(mn0, mnj); mx0 = fmaxf(mx0, mxj); }
            if (j == 1) { mn1 = fminf(mn1, mnj); mx1 = fmaxf(mx1, mxj); }
            if (j == 2) { mn2 = fminf(mn2, mnj); mx2 = fmaxf(mx2, mxj); }
            if (j == 3) { mn3 = fminf(mn3, mnj); mx3 = fmaxf(mx3, mxj); }
            int w = __builtin_amdgcn_cvt_pk_fp8_f32(v0, v1, 0, false);
            w = __builtin_amdgcn_cvt_pk_fp8_f32(v2, v3, w, true);
            tile32[4 * pc + j][q] = (unsigned int)w;
        }
    }
    smn[ph][4 * pc + 0] = mn0; smx[ph][4 * pc + 0] = mx0;
    smn[ph][4 * pc + 1] = mn1; smx[ph][4 * pc + 1] = mx1;
    smn[ph][4 * pc + 2] = mn2; smx[ph][4 * pc + 2] = mx2;
    smn[ph][4 * pc + 3] = mn3; smx[ph][4 * pc + 3] = mx3;
    __syncthreads();

    int tp = threadIdx.x;
    cmn[p0 + tp] = fminf(fminf(smn[0][tp], smn[1][tp]), fminf(smn[2][tp], smn[3][tp]));
    cmx[p0 + tp] = fmaxf(fmaxf(smx[0][tp], smx[1][tp]), fmaxf(smx[2][tp], smx[3][tp]));

    // write out: per j, wave covers 2 positions x 32 quads = 256 B contiguous
    #pragma unroll
    for (int j = 0; j < 32; ++j) {
        int u   = j * BLOCK + threadIdx.x;
        int pos = u >> 5;
        int c4  = u & 31;
        rt32[(((size_t)(p0 + pos)) << 5) + c4] = tile32[pos][c4];
    }
}

// ---------- fp8 quad decode + pow-accumulate helpers ----------
__device__ inline float pw_term(float va, float vb, float sc1, float nsc2, float K, float pw) {
    float d = fmaf(va, sc1, fmaf(vb, nsc2, K));
    // |d|^pw = exp2(pw * log2(|d|)); d==0 -> exp2(-inf) = 0, correct.
    return __builtin_amdgcn_exp2f(pw * __builtin_amdgcn_logf(fabsf(d)));
}

__device__ inline float quad_acc(unsigned int wa, unsigned int wb,
                                 float sc1, float nsc2, float K, float pw) {
    floatx2 a0 = __builtin_amdgcn_cvt_pk_f32_fp8((int)wa, false);
    floatx2 a1 = __builtin_amdgcn_cvt_pk_f32_fp8((int)wa, true);
    floatx2 b0 = __builtin_amdgcn_cvt_pk_f32_fp8((int)wb, false);
    floatx2 b1 = __builtin_amdgcn_cvt_pk_f32_fp8((int)wb, true);
    return pw_term(a0.x, b0.x, sc1, nsc2, K, pw) + pw_term(a0.y, b0.y, sc1, nsc2, K, pw)
         + pw_term(a1.x, b1.x, sc1, nsc2, K, pw) + pw_term(a1.y, b1.y, sc1, nsc2, K, pw);
}

// ---------- K2: per-pair loss (patch minmax prologue + fp8 gather) ----------
__global__ __launch_bounds__(BLOCK) void pair_loss_kernel(
    const uint4* __restrict__ rt,             // fp8 tensor, 8 uint4 per position
    const int* __restrict__ ts1, const int* __restrict__ ys1, const int* __restrict__ xs1,
    const int* __restrict__ ts2, const int* __restrict__ ys2, const int* __restrict__ xs2,
    const int* __restrict__ pair_type,
    const float* __restrict__ powers,
    const float* __restrict__ plus,
    const float* __restrict__ cmn, const float* __restrict__ cmx,
    float* __restrict__ per_out) {
    int i = blockIdx.x;
    int t1 = ts1[i], y1 = ys1[i], x1 = xs1[i];
    int t2 = ts2[i], y2 = ys2[i], x2 = xs2[i];
    int p1 = t1 * HW + y1 * WFD + x1;
    int p2 = t2 * HW + y2 * WFD + x2;

    // --- patch min/max from per-position channel min/max (L2-hot, 1024 loads) ---
    int dy = threadIdx.x >> 4, dx = threadIdx.x & 15;
    int q1 = p1 + dy * WFD + dx;
    int q2 = p2 + dy * WFD + dx;
    float a0 = cmn[q1], a1 = cmx[q1];
    float b0 = cmn[q2], b1 = cmx[q2];
    #pragma unroll
    for (int off = 32; off > 0; off >>= 1) {
        a0 = fminf(a0, __shfl_down(a0, off));
        a1 = fmaxf(a1, __shfl_down(a1, off));
        b0 = fminf(b0, __shfl_down(b0, off));
        b1 = fmaxf(b1, __shfl_down(b1, off));
    }
    __shared__ float red[4][4];
    int wave = threadIdx.x >> 6;
    if ((threadIdx.x & 63) == 0) {
        red[wave][0] = a0; red[wave][1] = a1; red[wave][2] = b0; red[wave][3] = b1;
    }
    __syncthreads();
    float mn1 = fminf(fminf(red[0][0], red[1][0]), fminf(red[2][0], red[3][0]));
    float mx1 = fmaxf(fmaxf(red[0][1], red[1][1]), fmaxf(red[2][1], red[3][1]));
    float mn2 = fminf(fminf(red[0][2], red[1][2]), fminf(red[2][2], red[3][2]));
    float mx2 = fmaxf(fmaxf(red[0][3], red[1][3]), fmaxf(red[2][3], red[3][3]));

    float rg1 = mx1 - mn1, rg2 = mx2 - mn2;
    float sc1 = (rg1 != 0.0f) ? (1.0f / rg1) : 1.0f;
    float sh1 = (rg1 != 0.0f) ? mn1 : 0.0f;
    float sc2 = (rg2 != 0.0f) ? (1.0f / rg2) : 1.0f;
    float sh2 = (rg2 != 0.0f) ? mn2 : 0.0f;
    float nsc2 = -sc2;
    float K = sh2 * sc2 - sh1 * sc1;

    int   ptype = pair_type[i];
    float pw    = powers[ptype];

    // --- main gather: thread = (c16 = tid&7 [16 ch], pdx = (tid>>3)&15, dyb = tid>>7) ---
    // wave-load = 8 lanes x 16 B per position = full 128 B position, 1 KB/wave contiguous.
    int c16 = threadIdx.x & 7;
    int pdx = (threadIdx.x >> 3) & 15;
    int dyb = threadIdx.x >> 7;
    const uint4* A = rt + (((size_t)(p1 + pdx)) << 3) + c16;
    const uint4* B = rt + (((size_t)(p2 + pdx)) << 3) + c16;
    const size_t RSTR = (size_t)WFD << 3;     // uint4 per image row

    float acc = 0.0f;
    #pragma unroll
    for (int j = 0; j < 8; ++j) {
        size_t off = (size_t)(dyb + 2 * j) * RSTR;
        uint4 wa = A[off];
        uint4 wb = B[off];
        acc += quad_acc(wa.x, wb.x, sc1, nsc2, K, pw);
        acc += quad_acc(wa.y, wb.y, sc1, nsc2, K, pw);
        acc += quad_acc(wa.z, wb.z, sc1, nsc2, K, pw);
        acc += quad_acc(wa.w, wb.w, sc1, nsc2, K, pw);
    }
    // block sum-reduce
    for (int off = 32; off > 0; off >>= 1) acc += __shfl_down(acc, off);
    __shared__ float ssum[BLOCK / 64];
    if ((threadIdx.x & 63) == 0) ssum[wave] = acc;
    __syncthreads();
    if (threadIdx.x == 0) {
        float total = ssum[0] + ssum[1] + ssum[2] + ssum[3];
        float dmean = total * (1.0f / (float)PATCH_ELEMS);
        float per = (ptype == 2) ? dmean : (1.0f / (1.0f + dmean));
        per += (ptype == 0) ? 0.0f : plus[0] * 0.5f;
        per_out[i] = per;
    }
}

// ---------- K3: mean over pairs ----------
__global__ __launch_bounds__(BLOCK) void final_mean_kernel(
    const float* __restrict__ per_out, float* __restrict__ out) {
    float acc = 0.0f;
    for (int i = threadIdx.x; i < NPAIR; i += BLOCK) acc += per_out[i];
    for (int off = 32; off > 0; off >>= 1) acc += __shfl_down(acc, off);
    __shared__ float ssum[BLOCK / 64];
    int wave = threadIdx.x >> 6;
    if ((threadIdx.x & 63) == 0) ssum[wave] = acc;
    __syncthreads();
    if (threadIdx.x == 0) {
        float total = ssum[0] + ssum[1] + ssum[2] + ssum[3];
        out[0] = total * (1.0f / (float)NPAIR);
    }
}

extern "C" void kernel_launch(void* const* d_in, const int* in_sizes, int n_in,
                              void* d_out, int out_size, void* d_ws, size_t ws_size,
                              hipStream_t stream) {
    const float* resp      = (const float*)d_in[0];
    const int*   ys1       = (const int*)d_in[1];
    const int*   xs1       = (const int*)d_in[2];
    const int*   ts1       = (const int*)d_in[3];
    const int*   ys2       = (const int*)d_in[4];
    const int*   xs2       = (const int*)d_in[5];
    const int*   ts2       = (const int*)d_in[6];
    const int*   pair_type = (const int*)d_in[7];
    const float* powers    = (const float*)d_in[8];
    const float* plus      = (const float*)d_in[9];
    float*       out       = (float*)d_out;

    // Workspace: fp8 tensor (25.2 MB) + cmn/cmx (1.5 MB) + per_out
    unsigned int* rt32 = (unsigned int*)d_ws;
    float* cmn     = (float*)(rt32 + (size_t)POS * 32);
    float* cmx     = cmn + POS;
    float* per_out = cmx + POS;

    transpose_minmax_kernel<<<POS / TP, BLOCK, 0, stream>>>(resp, rt32, cmn, cmx);

    pair_loss_kernel<<<NPAIR, BLOCK, 0, stream>>>(
        (const uint4*)rt32, ts1, ys1, xs1, ts2, ys2, xs2, pair_type, powers, plus,
        cmn, cmx, per_out);

    final_mean_kernel<<<1, BLOCK, 0, stream>>>(per_out, out);
}